// Round 3
// baseline (241.158 us; speedup 1.0000x reference)
//
#include <hip/hip_runtime.h>

// Planar normalizing flow, restructured (all-f32 I/O per the reference):
//   p = X * W^T + b  (GEMM1)
//   t_k = tanh(p_k + sum_{j<k} t_j * G[j,k]),  G[j,k] = uhat_j . w_k
//   z   = X + T * Uhat  (GEMM2)
//   logdet_k = log(|1 + (1-t_k^2) * c_k| + 1e-8),  c_k = softplus(w_k.u_k) - 1

#define B_ 65536
#define D_ 256
#define K_ 32

// table layout (floats):
//   wT    [256*32] @ 0      : wT[d*32+k]   = w[k][d]
//   uhatT [256*32] @ 8192   : uhatT[d*32+k]= uhat[k][d]
//   Gt    [32*32]  @ 16384  : Gt[k*32+j]   = uhat_j . w_k
//   cs    [32]     @ 17408
//   bfs   [32]     @ 17440
__device__ float g_ws[17472];

__global__ __launch_bounds__(256) void nf_pre(const float* __restrict__ u_in,
                                              const float* __restrict__ w_in,
                                              const float* __restrict__ b_in) {
  __shared__ float wls[32 * 257];  // 34KB total LDS (safely < 64KB)
  __shared__ float red[256];
  __shared__ float dots[128];
  __shared__ float coefk_s;
  const int t = threadIdx.x;
  const int myk = blockIdx.x;

  // stage w (32x256 f32) -> LDS, padded stride 257
  {
    const float4* wp = (const float4*)w_in;
#pragma unroll
    for (int j = 0; j < 8; ++j) {
      int idx = j * 256 + t;  // float4 index, coalesced
      float4 v = wp[idx];
      int e = idx * 4;
      int k = e >> 8, d = e & 255;
      wls[k * 257 + d]     = v.x;
      wls[k * 257 + d + 1] = v.y;
      wls[k * 257 + d + 2] = v.z;
      wls[k * 257 + d + 3] = v.w;
    }
  }
  __syncthreads();

  // 128 dots x 2 half-threads: typ0 u_j.w_j, typ1 w_j.w_j, typ2 w_j.w_k, typ3 u_j.w_k
  {
    int id = t & 127, hh = t >> 7;
    int j = id & 31, typ = id >> 5;
    const float* A;
    const float* Bp;
    if (typ == 0)      { A = u_in + j * 256; Bp = wls + j * 257; }
    else if (typ == 1) { A = wls + j * 257;  Bp = wls + j * 257; }
    else if (typ == 2) { A = wls + j * 257;  Bp = wls + myk * 257; }
    else               { A = u_in + j * 256; Bp = wls + myk * 257; }
    float acc = 0.f;
    int d0 = hh * 128;
#pragma unroll 8
    for (int d = 0; d < 128; ++d) acc = fmaf(A[d0 + d], Bp[d0 + d], acc);
    red[t] = acc;
  }
  __syncthreads();
  if (t < 128) dots[t] = red[t] + red[t + 128];
  __syncthreads();

  float* wT = g_ws;
  float* uhatT = g_ws + 8192;
  float* Gt = g_ws + 16384;
  float* cs = g_ws + 17408;
  float* bfs = g_ws + 17440;

  if (t < 32) {
    float wu = dots[t], ww = dots[32 + t], wkw = dots[64 + t], ukw = dots[96 + t];
    float sp = fmaxf(wu, 0.f) + log1pf(__expf(-fabsf(wu)));
    float coef = (sp - 1.f - wu) / ww;
    Gt[myk * 32 + t] = fmaf(coef, wkw, ukw);
    if (t == myk) {
      cs[myk] = sp - 1.f;
      bfs[myk] = b_in[myk];
      coefk_s = coef;
    }
  }
  __syncthreads();
  {
    float coefk = coefk_s;
    float wv = wls[myk * 257 + t];
    float uhv = fmaf(coefk, wv, u_in[myk * 256 + t]);
    wT[t * 32 + myk] = wv;
    uhatT[t * 32 + myk] = uhv;
  }
}

// Main kernel: 512 blocks x 256 threads. 128 rows/block, 2 wave-halves per row
// (waves 0,2 = half 0 -> cols [s*64, s*64+32); waves 1,3 = half 1 -> +32).
__global__ __launch_bounds__(256) void nf_main(const float* __restrict__ X,
                                               float* __restrict__ out) {
  __shared__ float Xt[64 * 129];    // staged X chunk, transposed [c_local][row]; aliased as p_lds
  __shared__ float tls[128 * 33];   // t values per row

  const int t = threadIdx.x;
  const int lane = t & 63;
  const int r = ((t >> 7) << 6) | lane;  // row-in-block 0..127
  const int half = __builtin_amdgcn_readfirstlane((t >> 6) & 1);
  const int hb = half * 32;
  const int row0 = blockIdx.x * 128;
  const size_t grow = (size_t)(row0 + r);
  const int r_ld = t >> 1, q = t & 1;  // staging assignment

  const float* __restrict__ wT = g_ws;
  const float* __restrict__ uhatT = g_ws + 8192;
  const float* __restrict__ Gt = g_ws + 16384;
  const float* __restrict__ cs = g_ws + 17408;
  const float* __restrict__ bfs = g_ws + 17440;

  float4 pf[8];

  auto load_stage = [&](int s) {
    const float4* xp = (const float4*)X + (size_t)(row0 + r_ld) * 64 + s * 16 + q * 8;
#pragma unroll
    for (int j = 0; j < 8; ++j) pf[j] = xp[j];
  };
  auto store_stage = [&]() {
#pragma unroll
    for (int j = 0; j < 8; ++j) {
      int c0 = q * 32 + j * 4;
      Xt[(c0 + 0) * 129 + r_ld] = pf[j].x;
      Xt[(c0 + 1) * 129 + r_ld] = pf[j].y;
      Xt[(c0 + 2) * 129 + r_ld] = pf[j].z;
      Xt[(c0 + 3) * 129 + r_ld] = pf[j].w;
    }
  };

  float p[32];
#pragma unroll
  for (int k = 0; k < 32; ++k) p[k] = 0.f;

  // ---------------- phase 1: p = X . w (this thread's half of columns) -------
  load_stage(0);
  for (int s = 0; s < 4; ++s) {
    store_stage();
    __syncthreads();
    if (s < 3) load_stage(s + 1);
#pragma unroll
    for (int c = 0; c < 32; ++c) {
      float xc = Xt[(hb + c) * 129 + r];
      const float* wp = wT + (s * 64 + hb + c) * 32;  // wave-uniform -> s_load
#pragma unroll
      for (int k = 0; k < 32; ++k) p[k] = fmaf(xc, wp[k], p[k]);
    }
    __syncthreads();
  }

  // ---------------- p exchange + recurrence (half 1 computes) ---------------
  float* plds = Xt;  // alias: Xt staging no longer live
  if (half == 0) {
#pragma unroll
    for (int k = 0; k < 32; ++k) plds[r * 33 + k] = p[k];
  }
  load_stage(0);  // prefetch phase-3 stage 0 (regs only)
  __syncthreads();

  float tv[32];
  if (half == 1) {
    float pfull[32];
#pragma unroll
    for (int k = 0; k < 32; ++k) pfull[k] = p[k] + plds[r * 33 + k] + bfs[k];
#pragma unroll
    for (int k = 0; k < 32; ++k) {
      float la = pfull[k], lb = 0.f;
      const float* gp = Gt + k * 32;  // wave-uniform
#pragma unroll
      for (int j = 0; j + 1 < k; j += 2) {
        la = fmaf(tv[j], gp[j], la);
        lb = fmaf(tv[j + 1], gp[j + 1], lb);
      }
      if (k & 1) la = fmaf(tv[k - 1], gp[k - 1], la);
      float lin = la + lb;
      float e = __expf(2.f * lin);
      float tk = 1.f - 2.f / (e + 1.f);
      tv[k] = tk;
      tls[r * 33 + k] = tk;
      float val = fabsf(fmaf(1.f - tk * tk, cs[k], 1.f)) + 1e-8f;
      out[(size_t)B_ * D_ + (size_t)k * B_ + grow] = __logf(val);
    }
  }
  __syncthreads();
#pragma unroll
  for (int k = 0; k < 32; ++k) tv[k] = tls[r * 33 + k];

  // ---------------- phase 3: z = X + T . uhat, write f32 ---------------------
  for (int s = 0; s < 4; ++s) {
    store_stage();
    __syncthreads();
    if (s < 3) load_stage(s + 1);
    float4 ov[8];
#pragma unroll
    for (int c2 = 0; c2 < 8; ++c2) {
      float zz[4];
#pragma unroll
      for (int m = 0; m < 4; ++m) {
        int cl = hb + c2 * 4 + m;
        float z0 = Xt[cl * 129 + r];
        const float* up = uhatT + (s * 64 + cl) * 32;  // wave-uniform
#pragma unroll
        for (int k = 0; k < 32; ++k) z0 = fmaf(tv[k], up[k], z0);
        zz[m] = z0;
      }
      ov[c2] = make_float4(zz[0], zz[1], zz[2], zz[3]);
    }
    float4* op = (float4*)(out + grow * 256 + s * 64 + hb);
#pragma unroll
    for (int c2 = 0; c2 < 8; ++c2) op[c2] = ov[c2];
    __syncthreads();
  }
}

extern "C" void kernel_launch(void* const* d_in, const int* in_sizes, int n_in,
                              void* d_out, int out_size, void* d_ws, size_t ws_size,
                              hipStream_t stream) {
  const float* X = (const float*)d_in[0];
  // d_in[1] = h : unused by the math
  const float* u = (const float*)d_in[2];
  const float* w = (const float*)d_in[3];
  const float* b = (const float*)d_in[4];
  float* out = (float*)d_out;

  nf_pre<<<32, 256, 0, stream>>>(u, w, b);
  nf_main<<<B_ / 128, 256, 0, stream>>>(X, out);
}

// Round 4
// 209.413 us; speedup vs baseline: 1.1516x; 1.1516x over previous
//
#include <hip/hip_runtime.h>

// Planar NF, fully fused single kernel.
//   p = X.W^T ; t_k = tanh(p_k + b_k + sum_{j<k} t_j G[k][j]) ; z = X + T.Uhat
//   G[k][j] = uhat_j . w_k ; c_k = w_k.uhat_k = softplus(w.u)-1
// All operands LDS-resident; per-lane-distinct ds_read_b128 (no SMEM scalarization).
// Lane tile: 4 rows x 8 k (phase1) / 4 rows x 8 cols (phase3).

#define B_ 65536
#define D_ 256
#define K_ 32
#define ROWS 256
#define XT_STRIDE 264
#define UT_STRIDE 260

__global__ __launch_bounds__(256) void nf_fused(const float* __restrict__ X,
                                                const float* __restrict__ u_in,
                                                const float* __restrict__ w_in,
                                                const float* __restrict__ b_in,
                                                float* __restrict__ out) {
  // wT1: w as [d][k] (d*32+k) for phase 1; reused as T_lds [k][r] (k*256+r) after phase 1.
  // uT2: u as [k][d] (k*260+d); becomes uhat in place.
  // XtP: X staging [c][r] (c*264+r); reused as P [r][k] (r*32+k) between phases; also gen scratch.
  __shared__ float wT1[8192];
  __shared__ float uT2[32 * UT_STRIDE];
  __shared__ float XtP[8448];
  __shared__ float Gm[32 * 33];
  __shared__ float cs_s[32], coefs_s[32], bfs_s[32];

  const int t = threadIdx.x;
  const int lane = t & 63;
  const int wv = t >> 6;         // wave 0..3
  const int rg = lane >> 2;      // 0..15
  const int kq = lane & 3;       // 0..3 (k-octet in phase1, col-octet in phase3)
  const int row0 = blockIdx.x * ROWS;
  const int rp = t & 127;        // staging row-pair
  const int ch = t >> 7;         // staging col half
  const int xoff = wv * 64 + rg * 4;  // this lane's 4-row base (row-in-block)
  const int kw = t >> 3;         // gen: k row 0..31
  const int d0g = (t & 7) * 32;  // gen: d chunk

  // ---------------- table gen step 0: stage w -> wT1[d][k], u -> uhat buf ----
  {
    float4 tmp[8];
    const float4* wp = (const float4*)(w_in + kw * 256 + d0g);
#pragma unroll
    for (int j = 0; j < 8; ++j) tmp[j] = wp[j];
#pragma unroll
    for (int j = 0; j < 8; ++j) {
      wT1[(d0g + j * 4 + 0) * 32 + kw] = tmp[j].x;
      wT1[(d0g + j * 4 + 1) * 32 + kw] = tmp[j].y;
      wT1[(d0g + j * 4 + 2) * 32 + kw] = tmp[j].z;
      wT1[(d0g + j * 4 + 3) * 32 + kw] = tmp[j].w;
    }
    const float4* up = (const float4*)(u_in + kw * 256 + d0g);
#pragma unroll
    for (int j = 0; j < 8; ++j) tmp[j] = up[j];
    float4* ud = (float4*)&uT2[kw * UT_STRIDE + d0g];
#pragma unroll
    for (int j = 0; j < 8; ++j) ud[j] = tmp[j];
    if (t < 32) bfs_s[t] = b_in[t];
  }

  // phase-1 stage-0 prefetch (registers only; hides behind table gen)
  float4 pf[8];
  const float* xbase = X + (size_t)(row0 + 2 * rp) * 256 + ch * 16;
  auto load_stage = [&](int s) {
    const float4* a = (const float4*)(xbase + s * 32);
    const float4* b = (const float4*)(xbase + 256 + s * 32);
#pragma unroll
    for (int j = 0; j < 4; ++j) pf[j] = a[j];
#pragma unroll
    for (int j = 0; j < 4; ++j) pf[4 + j] = b[j];
  };
  auto store_stage = [&]() {
#pragma unroll
    for (int cc = 0; cc < 16; ++cc) {
      const float* fa = (const float*)&pf[cc >> 2];
      const float* fb = (const float*)&pf[4 + (cc >> 2)];
      *(float2*)&XtP[(ch * 16 + cc) * XT_STRIDE + 2 * rp] =
          make_float2(fa[cc & 3], fb[cc & 3]);
    }
  };
  load_stage(0);
  __syncthreads();

  // ---------------- gen step 1: partial dots wu_j, ww_j ----------------------
  {
    int qd = t >> 6, which = (t >> 5) & 1, j = t & 31;
    int dlo = qd * 64;
    float acc = 0.f;
    if (which == 0) {
#pragma unroll 8
      for (int d = 0; d < 64; ++d)
        acc = fmaf(wT1[(dlo + d) * 32 + j], uT2[j * UT_STRIDE + dlo + d], acc);
    } else {
#pragma unroll 8
      for (int d = 0; d < 64; ++d) {
        float wvv = wT1[(dlo + d) * 32 + j];
        acc = fmaf(wvv, wvv, acc);
      }
    }
    XtP[t] = acc;  // scratch
  }
  __syncthreads();
  if (t < 32) {
    float wu = XtP[t] + XtP[64 + t] + XtP[128 + t] + XtP[192 + t];
    float ww = XtP[32 + t] + XtP[96 + t] + XtP[160 + t] + XtP[224 + t];
    float sp = fmaxf(wu, 0.f) + log1pf(__expf(-fabsf(wu)));
    coefs_s[t] = (sp - 1.f - wu) / ww;
    cs_s[t] = sp - 1.f;
  }
  __syncthreads();

  // ---------------- gen step 2: uhat = u + coef_k * w, in place --------------
  {
    float ck = coefs_s[kw];
    float4* ud = (float4*)&uT2[kw * UT_STRIDE + d0g];
#pragma unroll
    for (int j = 0; j < 8; ++j) {
      float4 uvv = ud[j];
      uvv.x = fmaf(ck, wT1[(d0g + j * 4 + 0) * 32 + kw], uvv.x);
      uvv.y = fmaf(ck, wT1[(d0g + j * 4 + 1) * 32 + kw], uvv.y);
      uvv.z = fmaf(ck, wT1[(d0g + j * 4 + 2) * 32 + kw], uvv.z);
      uvv.w = fmaf(ck, wT1[(d0g + j * 4 + 3) * 32 + kw], uvv.w);
      ud[j] = uvv;
    }
  }
  __syncthreads();

  // ---------------- gen step 3: G[k][j] = uhat_j . w_k -----------------------
  {
    int j = t & 31, kg = t >> 5;  // kg 0..7; k = kg + 8i
    float g0 = 0.f, g1 = 0.f, g2 = 0.f, g3 = 0.f;
#pragma unroll 4
    for (int d = 0; d < 256; ++d) {
      float uj = uT2[j * UT_STRIDE + d];
      g0 = fmaf(uj, wT1[d * 32 + kg], g0);
      g1 = fmaf(uj, wT1[d * 32 + kg + 8], g1);
      g2 = fmaf(uj, wT1[d * 32 + kg + 16], g2);
      g3 = fmaf(uj, wT1[d * 32 + kg + 24], g3);
    }
    Gm[kg * 33 + j] = g0;
    Gm[(kg + 8) * 33 + j] = g1;
    Gm[(kg + 16) * 33 + j] = g2;
    Gm[(kg + 24) * 33 + j] = g3;
  }
  // (no extra sync: next sync below covers Gm before any reader)

  // ---------------- phase 1: p = X . w ---------------------------------------
  float p[4][8];
#pragma unroll
  for (int a = 0; a < 4; ++a)
#pragma unroll
    for (int b2 = 0; b2 < 8; ++b2) p[a][b2] = 0.f;

  for (int s = 0; s < 8; ++s) {
    store_stage();
    __syncthreads();
    if (s < 7) load_stage(s + 1);
#pragma unroll 8
    for (int d = 0; d < 32; ++d) {
      float4 xv = *(const float4*)&XtP[d * XT_STRIDE + xoff];
      const float* wrow = &wT1[(s * 32 + d) * 32 + kq * 8];
      float4 w0 = *(const float4*)wrow;
      float4 w1 = *(const float4*)(wrow + 4);
      const float xr[4] = {xv.x, xv.y, xv.z, xv.w};
      const float wk[8] = {w0.x, w0.y, w0.z, w0.w, w1.x, w1.y, w1.z, w1.w};
#pragma unroll
      for (int a = 0; a < 4; ++a)
#pragma unroll
        for (int b2 = 0; b2 < 8; ++b2) p[a][b2] = fmaf(xr[a], wk[b2], p[a][b2]);
    }
    __syncthreads();
  }

  // ---------------- dump p -> P (XtP region), layout [r][k] stride 32 --------
#pragma unroll
  for (int a = 0; a < 4; ++a) {
    float4* dst = (float4*)&XtP[(xoff + a) * 32 + kq * 8];
    dst[0] = make_float4(p[a][0], p[a][1], p[a][2], p[a][3]);
    dst[1] = make_float4(p[a][4], p[a][5], p[a][6], p[a][7]);
  }
  __syncthreads();
  load_stage(0);  // phase-3 prefetch (regs only)

  // ---------------- recurrence: one row per thread ---------------------------
  {
    float pfull[32];
    const float4* ps = (const float4*)&XtP[t * 32];
#pragma unroll
    for (int j = 0; j < 8; ++j) {
      float4 v = ps[j];
      pfull[j * 4 + 0] = v.x + bfs_s[j * 4 + 0];
      pfull[j * 4 + 1] = v.y + bfs_s[j * 4 + 1];
      pfull[j * 4 + 2] = v.z + bfs_s[j * 4 + 2];
      pfull[j * 4 + 3] = v.w + bfs_s[j * 4 + 3];
    }
    float tvv[32];
#pragma unroll
    for (int k = 0; k < 32; ++k) {
      float la = pfull[k], lb = 0.f;
      const float* gp = &Gm[k * 33];
#pragma unroll
      for (int j = 0; j + 1 < k; j += 2) {
        la = fmaf(tvv[j], gp[j], la);
        lb = fmaf(tvv[j + 1], gp[j + 1], lb);
      }
      if (k & 1) la = fmaf(tvv[k - 1], gp[k - 1], la);
      float lin = la + lb;
      float e = __expf(2.f * lin);
      float tk = 1.f - 2.f / (e + 1.f);
      tvv[k] = tk;
      wT1[k * 256 + t] = tk;  // T_lds [k][r]
      float val = fabsf(fmaf(1.f - tk * tk, cs_s[k], 1.f)) + 1e-8f;
      out[(size_t)B_ * D_ + (size_t)k * B_ + row0 + t] = __logf(val);
    }
  }
  __syncthreads();

  // ---------------- phase 3: z = X + T . uhat --------------------------------
  for (int s = 0; s < 8; ++s) {
    store_stage();
    __syncthreads();
    if (s < 7) load_stage(s + 1);
    float acc[4][8];
#pragma unroll
    for (int dd = 0; dd < 8; ++dd) {
      float4 xv = *(const float4*)&XtP[(kq * 8 + dd) * XT_STRIDE + xoff];
      acc[0][dd] = xv.x;
      acc[1][dd] = xv.y;
      acc[2][dd] = xv.z;
      acc[3][dd] = xv.w;
    }
#pragma unroll 8
    for (int k = 0; k < 32; ++k) {
      float4 t4 = *(const float4*)&wT1[k * 256 + xoff];
      const float* ur = &uT2[k * UT_STRIDE + s * 32 + kq * 8];
      float4 u0 = *(const float4*)ur;
      float4 u1 = *(const float4*)(ur + 4);
      const float tr[4] = {t4.x, t4.y, t4.z, t4.w};
      const float uk[8] = {u0.x, u0.y, u0.z, u0.w, u1.x, u1.y, u1.z, u1.w};
#pragma unroll
      for (int a = 0; a < 4; ++a)
#pragma unroll
        for (int b2 = 0; b2 < 8; ++b2) acc[a][b2] = fmaf(tr[a], uk[b2], acc[a][b2]);
    }
#pragma unroll
    for (int a = 0; a < 4; ++a) {
      float4* op = (float4*)(out + (size_t)(row0 + xoff + a) * 256 + s * 32 + kq * 8);
      op[0] = make_float4(acc[a][0], acc[a][1], acc[a][2], acc[a][3]);
      op[1] = make_float4(acc[a][4], acc[a][5], acc[a][6], acc[a][7]);
    }
    __syncthreads();
  }
}

extern "C" void kernel_launch(void* const* d_in, const int* in_sizes, int n_in,
                              void* d_out, int out_size, void* d_ws, size_t ws_size,
                              hipStream_t stream) {
  const float* X = (const float*)d_in[0];
  // d_in[1] = h : unused by the math
  const float* u = (const float*)d_in[2];
  const float* w = (const float*)d_in[3];
  const float* b = (const float*)d_in[4];
  float* out = (float*)d_out;

  nf_fused<<<B_ / ROWS, 256, 0, stream>>>(X, u, w, b, out);
}